// Round 1
// baseline (2364.856 us; speedup 1.0000x reference)
//
#include <hip/hip_runtime.h>
#include <math.h>

// Problem constants (BagOfConcepts): inp [8,4096,512] f32, codebook [4096,512] f32
constexpr int D  = 512;
constexpr int K  = 4096;
constexpr int BM = 64;   // tokens per block
constexpr int BN = 64;   // concepts per tile
constexpr int BD = 32;   // d-chunk staged in LDS
constexpr int PAD = 4;   // LDS pad (keeps float4 alignment: (BM+4)*4B row stride, 16B-aligned)

// ---------------- kernel 0: s_c[k] = sum_d codebook[k][d]^2 (f32) ----------------
__global__ __launch_bounds__(256)
void sc_kernel(const float* __restrict__ cb, float* __restrict__ sc) {
    const int row  = blockIdx.x * 4 + (threadIdx.x >> 6);
    const int lane = threadIdx.x & 63;
    const float* r = cb + (size_t)row * D + lane * 8;
    float4 v0 = *(const float4*)r;
    float4 v1 = *(const float4*)(r + 4);
    float s = v0.x * v0.x;
    s += v0.y * v0.y; s += v0.z * v0.z; s += v0.w * v0.w;
    s += v1.x * v1.x; s += v1.y * v1.y; s += v1.z * v1.z; s += v1.w * v1.w;
#pragma unroll
    for (int off = 1; off < 64; off <<= 1) s += __shfl_xor(s, off, 64);
    if (lane == 0) sc[row] = s;
}

// ---------------- kernel 1: tiled distance-argmin + gather ----------------
// thread layout: t in [0,256); tm = t>>4 (16 row-groups of 4 tokens), tn = t&15 (16 col-groups of 4 concepts)
__global__ __launch_bounds__(256)
void vq_kernel(const float* __restrict__ inp, const float* __restrict__ cb,
               const float* __restrict__ sc, float* __restrict__ out) {
    __shared__ __align__(16) float As[BD][BM + PAD];  // transposed: As[d][m]
    __shared__ __align__(16) float Bs[BD][BN + PAD];  // transposed: Bs[d][n]
    __shared__ float sx[BM];
    __shared__ float scs[BN];
    __shared__ int   bidx[BM];

    const int t  = threadIdx.x;
    const int m0 = blockIdx.x * BM;
    const int tm = t >> 4;
    const int tn = t & 15;
    const float FINF = __builtin_huge_valf();

    // ---- prologue: s_x for this block's 64 tokens (any f32 order is fine:
    // s_x is on the same f32 grid as the ref's, so differences are grid
    // multiples -> uniform shift of all scores -> argmin invariant) ----
    {
        const int r = t >> 2, p = t & 3;
        const float* row = inp + (size_t)(m0 + r) * D + p * 128;
        float s = 0.0f;
#pragma unroll
        for (int i = 0; i < 32; ++i) {
            float4 v = *(const float4*)(row + i * 4);
            s = fmaf(v.x, v.x, s); s = fmaf(v.y, v.y, s);
            s = fmaf(v.z, v.z, s); s = fmaf(v.w, v.w, s);
        }
        s += __shfl_xor(s, 1, 64);
        s += __shfl_xor(s, 2, 64);
        if (p == 0) sx[r] = s;
    }
    __syncthreads();

    float sxm[4];
#pragma unroll
    for (int i = 0; i < 4; ++i) sxm[i] = sx[tm * 4 + i];

    float runv[4] = {FINF, FINF, FINF, FINF};
    int   runi[4] = {0, 0, 0, 0};

    // staging address components
    const int dq = (t & 7) << 2;   // d offset within chunk: 0,4,...,28
    const int mr = t >> 3;         // row 0..31 (second half at +32)

#pragma unroll 1
    for (int kb = 0; kb < K; kb += BN) {
        __syncthreads();                       // prev epilogue done before scs overwrite
        if (t < BN) scs[t] = sc[kb + t];

        float acc[4][4];
#pragma unroll
        for (int i = 0; i < 4; ++i)
#pragma unroll
            for (int j = 0; j < 4; ++j) acc[i][j] = 0.0f;

#pragma unroll 1
        for (int db = 0; db < D; db += BD) {
            // issue global loads early (overlap with barrier wait)
            const float* ap = inp + (size_t)(m0 + mr) * D + db + dq;
            const float* bp = cb  + (size_t)(kb + mr) * D + db + dq;
            float4 av0 = *(const float4*)ap;
            float4 av1 = *(const float4*)(ap + (size_t)32 * D);
            float4 bv0 = *(const float4*)bp;
            float4 bv1 = *(const float4*)(bp + (size_t)32 * D);

            __syncthreads();   // all threads finished reading previous chunk

            As[dq + 0][mr] = av0.x; As[dq + 1][mr] = av0.y;
            As[dq + 2][mr] = av0.z; As[dq + 3][mr] = av0.w;
            As[dq + 0][mr + 32] = av1.x; As[dq + 1][mr + 32] = av1.y;
            As[dq + 2][mr + 32] = av1.z; As[dq + 3][mr + 32] = av1.w;
            Bs[dq + 0][mr] = bv0.x; Bs[dq + 1][mr] = bv0.y;
            Bs[dq + 2][mr] = bv0.z; Bs[dq + 3][mr] = bv0.w;
            Bs[dq + 0][mr + 32] = bv1.x; Bs[dq + 1][mr + 32] = bv1.y;
            Bs[dq + 2][mr + 32] = bv1.z; Bs[dq + 3][mr + 32] = bv1.w;

            __syncthreads();   // chunk staged

#pragma unroll
            for (int d = 0; d < BD; ++d) {
                const float4 a = *(const float4*)(&As[d][tm * 4]);
                const float4 b = *(const float4*)(&Bs[d][tn * 4]);
                float af[4] = {a.x, a.y, a.z, a.w};
                float bf[4] = {b.x, b.y, b.z, b.w};
#pragma unroll
                for (int i = 0; i < 4; ++i)
#pragma unroll
                    for (int j = 0; j < 4; ++j)
                        acc[i][j] = fmaf(af[i], bf[j], acc[i][j]);
            }
        }

        // ---- per-tile argmin epilogue (exact ref f32 quantization + first-index ties) ----
#pragma unroll
        for (int i = 0; i < 4; ++i) {
            float bv = FINF;
            int   bi = 0x7fffffff;
#pragma unroll
            for (int j = 0; j < 4; ++j) {
                const float p = acc[i][j];
                // v = fl32( fl32(s_x - 2*dot) + s_c )  -- matches (a - b) + c in the reference
                const float tmp = sxm[i] - 2.0f * p;     // 2*p exact; single rounding
                const float v   = tmp + scs[tn * 4 + j]; // second rounding
                const int  idx  = kb + tn * 4 + j;
                if (v < bv) { bv = v; bi = idx; }        // j ascending -> first-index ties
            }
            // reduce across the 16 tn-lanes (lexicographic min on (v, idx))
#pragma unroll
            for (int off = 1; off < 16; off <<= 1) {
                const float ov = __shfl_xor(bv, off, 64);
                const int   oi = __shfl_xor(bi, off, 64);
                if (ov < bv || (ov == bv && oi < bi)) { bv = ov; bi = oi; }
            }
            // kb ascending -> new idx always larger -> strict < keeps first-index semantics
            if (bv < runv[i]) { runv[i] = bv; runi[i] = bi; }
        }
    }

    if (tn == 0) {
#pragma unroll
        for (int i = 0; i < 4; ++i) bidx[tm * 4 + i] = runi[i];
    }
    __syncthreads();

    // ---- fused gather: bit-exact copy of selected codebook rows ----
#pragma unroll 1
    for (int q = t; q < BM * (D / 4); q += 256) {
        const int r = q >> 7;       // D/4 == 128
        const int c = (q & 127) * 4;
        const float4 v = *(const float4*)(cb + (size_t)bidx[r] * D + c);
        *(float4*)(out + (size_t)(m0 + r) * D + c) = v;
    }
}

extern "C" void kernel_launch(void* const* d_in, const int* in_sizes, int n_in,
                              void* d_out, int out_size, void* d_ws, size_t ws_size,
                              hipStream_t stream) {
    const float* inp = (const float*)d_in[0];   // [8*4096, 512] f32
    const float* cb  = (const float*)d_in[1];   // [4096, 512]  f32
    float* out = (float*)d_out;
    float* sc  = (float*)d_ws;                  // 4096 f32 = 16 KB scratch

    const int tokens = in_sizes[0] / D;         // 32768

    sc_kernel<<<K / 4, 256, 0, stream>>>(cb, sc);
    vq_kernel<<<tokens / BM, 256, 0, stream>>>(inp, cb, sc, out);
}

// Round 2
// 1006.526 us; speedup vs baseline: 2.3495x; 2.3495x over previous
//
#include <hip/hip_runtime.h>
#include <math.h>

// BagOfConcepts: inp [8,4096,512] f32, codebook [4096,512] f32
constexpr int D  = 512;
constexpr int K  = 4096;
constexpr int BM = 64;
constexpr int BN = 64;
constexpr int BD_LEG = 32;
constexpr int PAD = 4;

constexpr int   CAP    = 128;        // candidate list per token
#define MARGIN 2.5e-4f               // >= tie window 1.33e-4 (ulp(1024)*2 + 2*err_wc)

typedef short short8v __attribute__((ext_vector_type(8)));
typedef float f32x4   __attribute__((ext_vector_type(4)));

// ws layout (fast path)
constexpr size_t SC_OFF    = 0;           // 4096 f32 = 16384
constexpr size_t IDX_OFF   = 16384;       // 32768 i32 = 131072
constexpr size_t CB_HI_OFF = 147456;      // 4096*512 u16 = 4194304
constexpr size_t CB_LO_OFF = 4341760;     // 4096*512 u16
constexpr size_t WS_NEED   = 8536064;

__device__ inline void f32_split_bf16(float x, unsigned short& h, unsigned short& l) {
    unsigned u  = __float_as_uint(x);
    unsigned hr = u + 0x7FFFu + ((u >> 16) & 1u);      // RNE to bf16
    h = (unsigned short)(hr >> 16);
    float hv = __uint_as_float((unsigned)h << 16);
    float lo = x - hv;                                  // exact
    unsigned v  = __float_as_uint(lo);
    unsigned lr = v + 0x7FFFu + ((v >> 16) & 1u);
    l = (unsigned short)(lr >> 16);
}

// ---------------- sc: s_c[k] = sum_d cb[k][d]^2 (UNCHANGED from passing kernel) -------
__global__ __launch_bounds__(256)
void sc_kernel(const float* __restrict__ cb, float* __restrict__ sc) {
    const int row  = blockIdx.x * 4 + (threadIdx.x >> 6);
    const int lane = threadIdx.x & 63;
    const float* r = cb + (size_t)row * D + lane * 8;
    float4 v0 = *(const float4*)r;
    float4 v1 = *(const float4*)(r + 4);
    float s = v0.x * v0.x;
    s += v0.y * v0.y; s += v0.z * v0.z; s += v0.w * v0.w;
    s += v1.x * v1.x; s += v1.y * v1.y; s += v1.z * v1.z; s += v1.w * v1.w;
#pragma unroll
    for (int off = 1; off < 64; off <<= 1) s += __shfl_xor(s, off, 64);
    if (lane == 0) sc[row] = s;
}

// ---------------- split-convert f32 -> bf16 hi/lo planes ----------------
__global__ __launch_bounds__(256)
void cvt_split(const float* __restrict__ src, unsigned short* __restrict__ hi,
               unsigned short* __restrict__ lo) {
    const size_t g = ((size_t)blockIdx.x * 256 + threadIdx.x) * 8;
    float4 v0 = *(const float4*)(src + g);
    float4 v1 = *(const float4*)(src + g + 4);
    float xs[8] = {v0.x, v0.y, v0.z, v0.w, v1.x, v1.y, v1.z, v1.w};
    union { short8v v; unsigned short u[8]; } H, L;
#pragma unroll
    for (int i = 0; i < 8; ++i) f32_split_bf16(xs[i], H.u[i], L.u[i]);
    *(short8v*)(hi + g) = H.v;
    *(short8v*)(lo + g) = L.v;
}

// ---------------- exact sequential dot (bit-identical to legacy order) ----------------
__device__ float exact_dot512(const float* __restrict__ x, const float* __restrict__ c) {
    float s = 0.0f;
#pragma unroll 4
    for (int i = 0; i < 128; ++i) {
        const float4 xv = *(const float4*)(x + i * 4);
        const float4 cv = *(const float4*)(c + i * 4);
        s = fmaf(xv.x, cv.x, s); s = fmaf(xv.y, cv.y, s);
        s = fmaf(xv.z, cv.z, s); s = fmaf(xv.w, cv.w, s);
    }
    return s;
}

// ---------------- MFMA filter + exact rescue ----------------
// block: 256 thr (4 waves). 64 tokens/block. k-iter = 256 codes (wave w owns 64).
// d-chunk = 32 (one 16x16x32 K-step). 256 flat iters = 16 kiters x 16 chunks.
__global__ __launch_bounds__(256, 2)
void vq_mfma(const float* __restrict__ inp, const float* __restrict__ cb,
             const float* __restrict__ sc,
             const unsigned short* __restrict__ a_hi,
             const unsigned short* __restrict__ a_lo,
             const unsigned short* __restrict__ cb_hi,
             const unsigned short* __restrict__ cb_lo,
             int* __restrict__ out_idx) {
    // A chunk buffers: 2 bufs x 2 planes x 64 rows x (32+8 pad) ushorts
    __shared__ unsigned short A_lds[2 * 2 * 64 * 40];   // 20480 B
    __shared__ float sx[64];
    __shared__ unsigned int cnt[64];
    __shared__ unsigned short list[64 * CAP];           // 16 KB
    __shared__ unsigned long long keys[64];

    const int t    = threadIdx.x;
    const int m0   = blockIdx.x * 64;
    const int lane = t & 63;
    const int w    = t >> 6;
    const int l15  = lane & 15;
    const int lk   = lane >> 4;
    const float FINF = __builtin_huge_valf();

    // ---- s_x prologue: BIT-IDENTICAL to legacy ----
    {
        const int r = t >> 2, p = t & 3;
        const float* row = inp + (size_t)(m0 + r) * D + p * 128;
        float s = 0.0f;
#pragma unroll
        for (int i = 0; i < 32; ++i) {
            float4 v = *(const float4*)(row + i * 4);
            s = fmaf(v.x, v.x, s); s = fmaf(v.y, v.y, s);
            s = fmaf(v.z, v.z, s); s = fmaf(v.w, v.w, s);
        }
        s += __shfl_xor(s, 1, 64);
        s += __shfl_xor(s, 2, 64);
        if (p == 0) sx[r] = s;
    }
    if (t < 64) { cnt[t] = 0u; keys[t] = 0xFFFFFFFFFFFFFFFFull; }

    // staging coords: thread t stages (row=t>>2, seg=t&3) in BOTH planes
    const int srow = t >> 2;
    const int sseg = t & 3;
    const size_t a_gbase = (size_t)(m0 + srow) * D + sseg * 8;
    const int    a_lbase = srow * 40 + sseg * 8;

    f32x4 acc[4][4];
    float runmin[4][4];
#pragma unroll
    for (int i = 0; i < 4; ++i)
#pragma unroll
        for (int j = 0; j < 4; ++j) runmin[i][j] = FINF;

    short8v a_st0, a_st1;          // staged A (chunk iter+1)
    short8v b_cur[2][4], b_nxt[2][4];

    // prologue: chunk0 -> buf0 directly; preload chunk1 regs; preload B(iter0)
    a_st0 = *(const short8v*)(a_hi + a_gbase);
    a_st1 = *(const short8v*)(a_lo + a_gbase);
    *(short8v*)(&A_lds[a_lbase])        = a_st0;
    *(short8v*)(&A_lds[2560 + a_lbase]) = a_st1;
    a_st0 = *(const short8v*)(a_hi + a_gbase + 32);
    a_st1 = *(const short8v*)(a_lo + a_gbase + 32);
    {
        const int code0 = w * 64 + l15;
#pragma unroll
        for (int nt = 0; nt < 4; ++nt) {
            const size_t off = (size_t)(code0 + nt * 16) * D + lk * 8;
            b_cur[0][nt] = *(const short8v*)(cb_hi + off);
            b_cur[1][nt] = *(const short8v*)(cb_lo + off);
        }
    }
    __syncthreads();

    for (int iter = 0; iter < 256; ++iter) {
        const int chunk = iter & 15;
        const int kb    = (iter >> 4) << 8;
        const int buf   = iter & 1;

        if (chunk == 0) {
#pragma unroll
            for (int i = 0; i < 4; ++i)
#pragma unroll
                for (int j = 0; j < 4; ++j) acc[i][j] = f32x4{0.f, 0.f, 0.f, 0.f};
        }

        // 1) write staged A (chunk iter+1) into buf^1
        {
            const int wb = (buf ^ 1) * 5120 + a_lbase;
            *(short8v*)(&A_lds[wb])        = a_st0;
            *(short8v*)(&A_lds[wb + 2560]) = a_st1;
        }
        // 2) prefetch A chunk iter+2
        if (iter + 2 < 256) {
            const int d2 = ((iter + 2) & 15) << 5;
            a_st0 = *(const short8v*)(a_hi + a_gbase + d2);
            a_st1 = *(const short8v*)(a_lo + a_gbase + d2);
        }
        // 3) prefetch B iter+1
        if (iter + 1 < 256) {
            const int kb1 = ((iter + 1) >> 4) << 8;
            const int d1  = ((iter + 1) & 15) << 5;
            const int c0  = kb1 + w * 64 + l15;
#pragma unroll
            for (int nt = 0; nt < 4; ++nt) {
                const size_t off = (size_t)(c0 + nt * 16) * D + d1 + lk * 8;
                b_nxt[0][nt] = *(const short8v*)(cb_hi + off);
                b_nxt[1][nt] = *(const short8v*)(cb_lo + off);
            }
        }
        // 4) read A frags from buf, 48 MFMAs (hh, h*lo_c, lo_x*h)
        {
            short8v af0[4], af1[4];
            const int rb = buf * 5120;
#pragma unroll
            for (int mt = 0; mt < 4; ++mt) {
                const int ra = rb + (mt * 16 + l15) * 40 + lk * 8;
                af0[mt] = *(const short8v*)(&A_lds[ra]);
                af1[mt] = *(const short8v*)(&A_lds[ra + 2560]);
            }
#pragma unroll
            for (int mt = 0; mt < 4; ++mt)
#pragma unroll
                for (int nt = 0; nt < 4; ++nt) {
                    acc[mt][nt] = __builtin_amdgcn_mfma_f32_16x16x32_bf16(af0[mt], b_cur[0][nt], acc[mt][nt], 0, 0, 0);
                    acc[mt][nt] = __builtin_amdgcn_mfma_f32_16x16x32_bf16(af0[mt], b_cur[1][nt], acc[mt][nt], 0, 0, 0);
                    acc[mt][nt] = __builtin_amdgcn_mfma_f32_16x16x32_bf16(af1[mt], b_cur[0][nt], acc[mt][nt], 0, 0, 0);
                }
        }
        // 5) k-iter epilogue: running-min update + candidate collection
        if (chunk == 15) {
            const int code_base = kb + w * 64;
            float scv[4];
#pragma unroll
            for (int nt = 0; nt < 4; ++nt) scv[nt] = sc[code_base + nt * 16 + l15];
#pragma unroll
            for (int mt = 0; mt < 4; ++mt) {
#pragma unroll
                for (int r = 0; r < 4; ++r) {
                    float v0 = fmaf(-2.0f, acc[mt][0][r], scv[0]);
                    float v1 = fmaf(-2.0f, acc[mt][1][r], scv[1]);
                    float v2 = fmaf(-2.0f, acc[mt][2][r], scv[2]);
                    float v3 = fmaf(-2.0f, acc[mt][3][r], scv[3]);
                    float gm = fminf(fminf(v0, v1), fminf(v2, v3));
                    gm = fminf(gm, __shfl_xor(gm, 1, 64));
                    gm = fminf(gm, __shfl_xor(gm, 2, 64));
                    gm = fminf(gm, __shfl_xor(gm, 4, 64));
                    gm = fminf(gm, __shfl_xor(gm, 8, 64));
                    runmin[mt][r] = fminf(runmin[mt][r], gm);
                    const float th = runmin[mt][r] + MARGIN;
                    const int tok = mt * 16 + lk * 4 + r;
                    if (v0 <= th) { unsigned p = atomicAdd(&cnt[tok], 1u); if (p < CAP) list[tok * CAP + p] = (unsigned short)(code_base + l15); }
                    if (v1 <= th) { unsigned p = atomicAdd(&cnt[tok], 1u); if (p < CAP) list[tok * CAP + p] = (unsigned short)(code_base + 16 + l15); }
                    if (v2 <= th) { unsigned p = atomicAdd(&cnt[tok], 1u); if (p < CAP) list[tok * CAP + p] = (unsigned short)(code_base + 32 + l15); }
                    if (v3 <= th) { unsigned p = atomicAdd(&cnt[tok], 1u); if (p < CAP) list[tok * CAP + p] = (unsigned short)(code_base + 48 + l15); }
                }
            }
        }
#pragma unroll
        for (int nt = 0; nt < 4; ++nt) { b_cur[0][nt] = b_nxt[0][nt]; b_cur[1][nt] = b_nxt[1][nt]; }
        __syncthreads();
    }

    // ---- exact rescue: bit-identical scores for candidates; lexicographic (v, idx) min ----
    const float* inp_blk = inp + (size_t)m0 * D;
    for (int slot = t; slot < 64 * CAP; slot += 256) {
        const int tok = slot >> 7;
        const int j   = slot & (CAP - 1);
        unsigned n = cnt[tok]; if (n > CAP) n = CAP;
        if (j < (int)n) {
            const int code = list[slot];
            const float dot = exact_dot512(inp_blk + (size_t)tok * D, cb + (size_t)code * D);
            const float tmp = sx[tok] - 2.0f * dot;      // -2*dot exact => contraction-immune
            const float v   = tmp + sc[code];
            const unsigned long long key =
                ((unsigned long long)__float_as_uint(v) << 32) | (unsigned)code;
            atomicMin(&keys[tok], key);
        }
    }
    // overflow fallback (essentially never taken): full scan for that token
    for (int tok = 0; tok < 64; ++tok) {
        if (cnt[tok] > CAP) {
            for (int code = t; code < K; code += 256) {
                const float dot = exact_dot512(inp_blk + (size_t)tok * D, cb + (size_t)code * D);
                const float tmp = sx[tok] - 2.0f * dot;
                const float v   = tmp + sc[code];
                const unsigned long long key =
                    ((unsigned long long)__float_as_uint(v) << 32) | (unsigned)code;
                atomicMin(&keys[tok], key);
            }
        }
    }
    __syncthreads();
    if (t < 64) out_idx[m0 + t] = (int)(keys[t] & 0xFFFFFFFFull);
}

// ---------------- gather: bit-exact codebook row copy ----------------
__global__ __launch_bounds__(256)
void gather_kernel(const float* __restrict__ cb, const int* __restrict__ idx,
                   float* __restrict__ out) {
    const int m0 = blockIdx.x * 64;
    __shared__ int bidx[64];
    if (threadIdx.x < 64) bidx[threadIdx.x] = idx[m0 + threadIdx.x];
    __syncthreads();
    for (int q = threadIdx.x; q < 64 * (D / 4); q += 256) {
        const int r = q >> 7;
        const int c = (q & 127) * 4;
        *(float4*)(out + (size_t)(m0 + r) * D + c) = *(const float4*)(cb + (size_t)bidx[r] * D + c);
    }
}

// ================= LEGACY (round-1 passing kernel, fallback if ws too small) ==========
__global__ __launch_bounds__(256)
void vq_kernel(const float* __restrict__ inp, const float* __restrict__ cb,
               const float* __restrict__ sc, float* __restrict__ out) {
    __shared__ __align__(16) float As[BD_LEG][BM + PAD];
    __shared__ __align__(16) float Bs[BD_LEG][BN + PAD];
    __shared__ float sxl[BM];
    __shared__ float scs[BN];
    __shared__ int   bidx[BM];

    const int t  = threadIdx.x;
    const int m0 = blockIdx.x * BM;
    const int tm = t >> 4;
    const int tn = t & 15;
    const float FINF = __builtin_huge_valf();

    {
        const int r = t >> 2, p = t & 3;
        const float* row = inp + (size_t)(m0 + r) * D + p * 128;
        float s = 0.0f;
#pragma unroll
        for (int i = 0; i < 32; ++i) {
            float4 v = *(const float4*)(row + i * 4);
            s = fmaf(v.x, v.x, s); s = fmaf(v.y, v.y, s);
            s = fmaf(v.z, v.z, s); s = fmaf(v.w, v.w, s);
        }
        s += __shfl_xor(s, 1, 64);
        s += __shfl_xor(s, 2, 64);
        if (p == 0) sxl[r] = s;
    }
    __syncthreads();

    float sxm[4];
#pragma unroll
    for (int i = 0; i < 4; ++i) sxm[i] = sxl[tm * 4 + i];

    float runv[4] = {FINF, FINF, FINF, FINF};
    int   runi[4] = {0, 0, 0, 0};
    const int dq = (t & 7) << 2;
    const int mr = t >> 3;

#pragma unroll 1
    for (int kb = 0; kb < K; kb += BN) {
        __syncthreads();
        if (t < BN) scs[t] = sc[kb + t];

        float accl[4][4];
#pragma unroll
        for (int i = 0; i < 4; ++i)
#pragma unroll
            for (int j = 0; j < 4; ++j) accl[i][j] = 0.0f;

#pragma unroll 1
        for (int db = 0; db < D; db += BD_LEG) {
            const float* ap = inp + (size_t)(m0 + mr) * D + db + dq;
            const float* bp = cb  + (size_t)(kb + mr) * D + db + dq;
            float4 av0 = *(const float4*)ap;
            float4 av1 = *(const float4*)(ap + (size_t)32 * D);
            float4 bv0 = *(const float4*)bp;
            float4 bv1 = *(const float4*)(bp + (size_t)32 * D);
            __syncthreads();
            As[dq + 0][mr] = av0.x; As[dq + 1][mr] = av0.y;
            As[dq + 2][mr] = av0.z; As[dq + 3][mr] = av0.w;
            As[dq + 0][mr + 32] = av1.x; As[dq + 1][mr + 32] = av1.y;
            As[dq + 2][mr + 32] = av1.z; As[dq + 3][mr + 32] = av1.w;
            Bs[dq + 0][mr] = bv0.x; Bs[dq + 1][mr] = bv0.y;
            Bs[dq + 2][mr] = bv0.z; Bs[dq + 3][mr] = bv0.w;
            Bs[dq + 0][mr + 32] = bv1.x; Bs[dq + 1][mr + 32] = bv1.y;
            Bs[dq + 2][mr + 32] = bv1.z; Bs[dq + 3][mr + 32] = bv1.w;
            __syncthreads();
#pragma unroll
            for (int d = 0; d < BD_LEG; ++d) {
                const float4 a = *(const float4*)(&As[d][tm * 4]);
                const float4 b = *(const float4*)(&Bs[d][tn * 4]);
                float af[4] = {a.x, a.y, a.z, a.w};
                float bf[4] = {b.x, b.y, b.z, b.w};
#pragma unroll
                for (int i = 0; i < 4; ++i)
#pragma unroll
                    for (int j = 0; j < 4; ++j)
                        accl[i][j] = fmaf(af[i], bf[j], accl[i][j]);
            }
        }
#pragma unroll
        for (int i = 0; i < 4; ++i) {
            float bv = FINF;
            int   bi = 0x7fffffff;
#pragma unroll
            for (int j = 0; j < 4; ++j) {
                const float p = accl[i][j];
                const float tmp = sxm[i] - 2.0f * p;
                const float v   = tmp + scs[tn * 4 + j];
                const int  idx  = kb + tn * 4 + j;
                if (v < bv) { bv = v; bi = idx; }
            }
#pragma unroll
            for (int off = 1; off < 16; off <<= 1) {
                const float ov = __shfl_xor(bv, off, 64);
                const int   oi = __shfl_xor(bi, off, 64);
                if (ov < bv || (ov == bv && oi < bi)) { bv = ov; bi = oi; }
            }
            if (bv < runv[i]) { runv[i] = bv; runi[i] = bi; }
        }
    }
    if (tn == 0) {
#pragma unroll
        for (int i = 0; i < 4; ++i) bidx[tm * 4 + i] = runi[i];
    }
    __syncthreads();
#pragma unroll 1
    for (int q = t; q < BM * (D / 4); q += 256) {
        const int r = q >> 7;
        const int c = (q & 127) * 4;
        const float4 v = *(const float4*)(cb + (size_t)bidx[r] * D + c);
        *(float4*)(out + (size_t)(m0 + r) * D + c) = v;
    }
}

extern "C" void kernel_launch(void* const* d_in, const int* in_sizes, int n_in,
                              void* d_out, int out_size, void* d_ws, size_t ws_size,
                              hipStream_t stream) {
    const float* inp = (const float*)d_in[0];
    const float* cb  = (const float*)d_in[1];
    float* out = (float*)d_out;
    float* sc  = (float*)d_ws;
    const int tokens = in_sizes[0] / D;     // 32768

    if (ws_size >= WS_NEED && (tokens % 64) == 0 &&
        (size_t)out_size * sizeof(float) >= (size_t)tokens * D * 4) {
        int* idx = (int*)((char*)d_ws + IDX_OFF);
        unsigned short* cbh = (unsigned short*)((char*)d_ws + CB_HI_OFF);
        unsigned short* cbl = (unsigned short*)((char*)d_ws + CB_LO_OFF);
        unsigned short* ah  = (unsigned short*)d_out;               // d_out as scratch
        unsigned short* al  = ah + (size_t)tokens * D;

        sc_kernel<<<K / 4, 256, 0, stream>>>(cb, sc);
        cvt_split<<<(K * D) / 2048, 256, 0, stream>>>(cb, cbh, cbl);
        cvt_split<<<(tokens * D) / 2048, 256, 0, stream>>>(inp, ah, al);
        vq_mfma<<<tokens / 64, 256, 0, stream>>>(inp, cb, sc, ah, al, cbh, cbl, idx);
        gather_kernel<<<tokens / 64, 256, 0, stream>>>(cb, idx, out);
    } else {
        sc_kernel<<<K / 4, 256, 0, stream>>>(cb, sc);
        vq_kernel<<<tokens / BM, 256, 0, stream>>>(inp, cb, sc, out);
    }
}